// Round 2
// baseline (221.051 us; speedup 1.0000x reference)
//
#include <hip/hip_runtime.h>

#define NLAYERS 4

// tanh(a) = 1 - 2/(exp(2a)+1); saturates correctly to +-1 for |a| large.
// v_exp_f32 + v_rcp_f32: ~5 VALU ops, abs error ~1e-6 (threshold is 6.6e-2).
__device__ __forceinline__ float ftanh(float a) {
    float e = __expf(2.0f * a);
    return 1.0f - 2.0f * __builtin_amdgcn_rcpf(e + 1.0f);
}

__global__ __launch_bounds__(256) void fraud_fused(
    const float4* __restrict__ x4,
    const float* __restrict__ Ws, const float* __restrict__ bs,
    const float* __restrict__ scales, const float* __restrict__ shifts,
    const float* __restrict__ Wf, const float* __restrict__ bf,
    float2* __restrict__ out2, int n4)
{
    // Uniform-address param loads -> scalar loads, hoisted before the loop.
    float w[NLAYERS][2][2], b[NLAYERS][2], s[NLAYERS][2], t[NLAYERS][2];
#pragma unroll
    for (int l = 0; l < NLAYERS; ++l) {
        w[l][0][0] = Ws[l * 4 + 0];
        w[l][0][1] = Ws[l * 4 + 1];
        w[l][1][0] = Ws[l * 4 + 2];
        w[l][1][1] = Ws[l * 4 + 3];
        b[l][0] = bs[l * 2 + 0];
        b[l][1] = bs[l * 2 + 1];
        s[l][0] = scales[l * 2 + 0];
        s[l][1] = scales[l * 2 + 1];
        t[l][0] = shifts[l * 2 + 0];
        t[l][1] = shifts[l * 2 + 1];
    }
    float wf0 = Wf[0], wf1 = Wf[1], bfv = bf[0];

    int stride = gridDim.x * blockDim.x;
    for (int i = blockIdx.x * blockDim.x + threadIdx.x; i < n4; i += stride) {
        float4 v = x4[i];  // two rows: (v.x,v.y) and (v.z,v.w)
        float h0a = v.x, h1a = v.y;
        float h0b = v.z, h1b = v.w;
#pragma unroll
        for (int l = 0; l < NLAYERS; ++l) {
            float a0 = fmaf(w[l][0][0], h0a, fmaf(w[l][0][1], h1a, b[l][0]));
            float a1 = fmaf(w[l][1][0], h0a, fmaf(w[l][1][1], h1a, b[l][1]));
            h0a = fmaf(ftanh(a0), s[l][0], t[l][0]);
            h1a = fmaf(ftanh(a1), s[l][1], t[l][1]);
            float c0 = fmaf(w[l][0][0], h0b, fmaf(w[l][0][1], h1b, b[l][0]));
            float c1 = fmaf(w[l][1][0], h0b, fmaf(w[l][1][1], h1b, b[l][1]));
            h0b = fmaf(ftanh(c0), s[l][0], t[l][0]);
            h1b = fmaf(ftanh(c1), s[l][1], t[l][1]);
        }
        float oa = fmaf(wf0, h0a, fmaf(wf1, h1a, bfv));
        float ob = fmaf(wf0, h0b, fmaf(wf1, h1b, bfv));
        out2[i] = make_float2(oa, ob);
    }
}

extern "C" void kernel_launch(void* const* d_in, const int* in_sizes, int n_in,
                              void* d_out, int out_size, void* d_ws, size_t ws_size,
                              hipStream_t stream) {
    const float4* x4      = (const float4*)d_in[0];
    const float*  Ws      = (const float*)d_in[1];
    const float*  bs      = (const float*)d_in[2];
    const float*  scales  = (const float*)d_in[3];
    const float*  shifts  = (const float*)d_in[4];
    const float*  Wf      = (const float*)d_in[5];
    const float*  bf      = (const float*)d_in[6];
    float2* out2          = (float2*)d_out;

    int n4 = in_sizes[0] / 4;  // float4 covers 2 rows of [B,2]
    int threads = 256;
    int blocks = 4096;  // grid-stride; ~8 float4 iters/thread at B=16.7M
    fraud_fused<<<blocks, threads, 0, stream>>>(x4, Ws, bs, scales, shifts,
                                                Wf, bf, out2, n4);
}